// Round 10
// baseline (8971.295 us; speedup 1.0000x reference)
//
#include <hip/hip_runtime.h>
#include <stdint.h>

// ---------------- problem constants ----------------
#define TSTEPS 512
#define NB     256
#define DIN    85
#define DPAD   96
#define HID    512
#define ODIM   33
#define OPAD   48
#define TBROWS (TSTEPS*NB)
#define NBLK   256          // 16 strips x 16 parts; 57KB LDS -> 2 blocks/CU fit, residency-robust
#define SROWS  16
#define LROW   520          // padded LDS row stride (u16)

typedef unsigned int u32;
typedef unsigned short u16;
typedef unsigned long long u64;
typedef __bf16 bf16x8 __attribute__((ext_vector_type(8)));
typedef float  f32x4  __attribute__((ext_vector_type(4)));

__device__ __forceinline__ u16 f2bf(float f) {
  u32 u = __float_as_uint(f);
  return (u16)((u + 0x7FFFu + ((u >> 16) & 1u)) >> 16);   // RNE
}
__device__ __forceinline__ float bf2f(u16 h) {
  return __uint_as_float(((u32)h) << 16);
}
__device__ __forceinline__ bf16x8 bc8(uint4 v) { return __builtin_bit_cast(bf16x8, v); }
__device__ __forceinline__ f32x4 mfma_bf16(bf16x8 a, bf16x8 b, f32x4 c) {
  return __builtin_amdgcn_mfma_f32_16x16x32_bf16(a, b, c, 0, 0, 0);
}
__device__ __forceinline__ float fsigmoid(float x) { return 1.0f / (1.0f + __expf(-x)); }
__device__ __forceinline__ float ftanh(float x)    { return 2.0f / (1.0f + __expf(-2.0f*x)) - 1.0f; }

// agent-scope (LLC-coherent) relaxed ops for cross-block mutable data
__device__ __forceinline__ void st_u32_llc(u32* p, u32 v) {
  __hip_atomic_store(p, v, __ATOMIC_RELAXED, __HIP_MEMORY_SCOPE_AGENT);
}
__device__ __forceinline__ u64 ld_u64_llc(const u64* p) {
  return __hip_atomic_load(p, __ATOMIC_RELAXED, __HIP_MEMORY_SCOPE_AGENT);
}
#define POLL_FENCE() do { asm volatile("" ::: "memory"); __builtin_amdgcn_sched_barrier(0); } while (0)

// 2-bit generation tag embedded in a packed (hi16|lo16) u32: bit16 (hi LSB) and bit0 (lo LSB)
#define TAG2(u) ((((u) >> 15) & 2u) | ((u) & 1u))
// build tagged pack: impose hi tag bit, recompute lo against tagged hi, impose lo tag bit
__device__ __forceinline__ u32 pack_tagged(float v, u32 tg, u16* hi_clean) {
  u16 hc = f2bf(v);
  if (hi_clean) *hi_clean = hc;
  u16 hi = (u16)((hc & 0xFFFEu) | ((tg >> 1) & 1u));
  u16 lo = f2bf(v - bf2f(hi));
  lo = (u16)((lo & 0xFFFEu) | (tg & 1u));
  return ((u32)hi << 16) | (u32)lo;
}

// ---------------- prep: bf16 weight conversions ----------------
__global__ void __launch_bounds__(256) prep_kernel(
    const float* __restrict__ Whr, const float* __restrict__ Whz, const float* __restrict__ Whh,
    const float* __restrict__ Wxr, const float* __restrict__ Wxz, const float* __restrict__ Wxh,
    const float* __restrict__ Wro,
    u16* __restrict__ w_hb, u16* __restrict__ wx_hi, u16* __restrict__ wx_lo,
    u16* __restrict__ w_rob)
{
  int tid = blockIdx.x * blockDim.x + threadIdx.x;
  int np  = gridDim.x * blockDim.x;
  for (int i = tid; i < 3 * HID * HID; i += np) {
    int m = i / (HID * HID), r = i % (HID * HID);
    const float* src = (m == 0) ? Whr : ((m == 1) ? Whz : Whh);
    w_hb[i] = f2bf(src[r]);
  }
  for (int i = tid; i < 3 * HID * DPAD; i += np) {
    int m = i / (HID * DPAD), r = i % (HID * DPAD);
    int row = r / DPAD, k = r % DPAD;
    const float* src = (m == 0) ? Wxr : ((m == 1) ? Wxz : Wxh);
    u16 hi = 0, lo = 0;
    if (k < DIN) {
      float v = src[row * DIN + k];
      hi = f2bf(v);
      lo = f2bf(v - bf2f(hi));
    }
    wx_hi[i] = hi; wx_lo[i] = lo;
  }
  for (int i = tid; i < OPAD * HID; i += np) {
    int row = i / HID, k = i % HID;
    w_rob[i] = (row < ODIM) ? f2bf(Wro[row * HID + k]) : (u16)0;
  }
}

// ---------------- persistent recurrence kernel: pure tagged dataflow, no flags ----------------
__global__ void __launch_bounds__(256, 1) recur_kernel(
    const float* __restrict__ x,  const float* __restrict__ nr,
    const float* __restrict__ nz, const float* __restrict__ nh,
    const float* __restrict__ bhr, const float* __restrict__ bhz, const float* __restrict__ bhh,
    const u16* __restrict__ wx_hi, const u16* __restrict__ wx_lo, const u16* __restrict__ w_hb,
    u32* __restrict__ h_pk, u32* __restrict__ g_pk,
    u16* __restrict__ hs_out,
    const float* __restrict__ Wro, const float* __restrict__ bro, float* __restrict__ out,
    int do_c)
{
  __shared__ __attribute__((aligned(16))) u16 sBig[2 * SROWS * LROW];   // 33280 B (h planes / g planes)
  __shared__ __attribute__((aligned(16))) u16 sX[3][2][SROWS][104];     // 19968 B
  __shared__ __attribute__((aligned(16))) float sC[2][2][64][4];        // 4096 B (combine / C scratch)

  u16 (*sHh)[LROW] = (u16(*)[LROW])sBig;
  u16 (*sHl)[LROW] = (u16(*)[LROW])(sBig + SROWS * LROW);
  u16 (*sGh)[LROW] = sHh;
  u16 (*sGl)[LROW] = sHl;

  const int tid  = threadIdx.x;
  const int lane = tid & 63;
  const int wave = tid >> 6;
  const int strip = (int)blockIdx.x >> 4;    // 0..15
  const int part  = (int)blockIdx.x & 15;    // 0..15
  const int kh = wave >> 1;                  // k-half
  const int ct = wave & 1;                   // col-tile
  const int rowl  = lane & 15;
  const int rquad = lane >> 4;
  const int scol  = part * 32 + ct * 16 + rowl;   // this lane's output column

  const u16* WR = w_hb;
  const u16* WZ = w_hb + (size_t)HID * HID;
  const u16* WH = w_hb + (size_t)2 * HID * HID;
  const u16* WXRh = wx_hi;                          const u16* WXRl = wx_lo;
  const u16* WXZh = wx_hi + (size_t)HID * DPAD;     const u16* WXZl = wx_lo + (size_t)HID * DPAD;
  const u16* WXHh = wx_hi + (size_t)2 * HID * DPAD; const u16* WXHl = wx_lo + (size_t)2 * HID * DPAD;

  const float bRv = bhr[scol], bZv = bhz[scol], bHv = bhh[scol];

  float h_old[4] = {0.f, 0.f, 0.f, 0.f};
  float zv[4]    = {0.f, 0.f, 0.f, 0.f};

  // zero x k-pads once
  for (int c = tid; c < 3 * 2 * SROWS * (104 - DIN); c += 256) {
    int g = c / (2 * SROWS * 19), r1 = c % (2 * SROWS * 19);
    int pl = r1 / (SROWS * 19),   r2 = r1 % (SROWS * 19);
    int row = r2 / 19, k = DIN + r2 % 19;
    sX[g][pl][row][k] = 0;
  }
  // stage x(1)
  {
    const size_t xbase = (size_t)(strip * SROWS) * DIN;
    for (int c = tid; c < 3 * SROWS * DIN; c += 256) {
      int g = c / (SROWS * DIN), rem = c - g * (SROWS * DIN);
      int row = rem / DIN, k = rem - row * DIN;
      const float* nsrc = (g == 0) ? nr : ((g == 1) ? nz : nh);
      float v = x[xbase + rem] + nsrc[xbase + rem];
      u16 hi = f2bf(v);
      sX[g][0][row][k] = hi;
      sX[g][1][row][k] = f2bf(v - bf2f(hi));
    }
  }
  __syncthreads();

  for (int t = 1; t <= TSTEPS; ++t) {
    const u32 tg = (u32)(t & 3);

    // ================= PHASE A: stage h(t-1) with tag-retry =================
    {
      const u32 texp = (u32)((t - 1) & 3);
      const u64* hsrc = (const u64*)(h_pk + (size_t)((t - 1) & 1) * NB * HID)
                        + (size_t)strip * SROWS * 256;
      u64 hreg[SROWS];
      for (;;) {
        #pragma unroll
        for (int i = 0; i < SROWS; ++i)
          hreg[i] = ld_u64_llc(&hsrc[(size_t)i * 256 + tid]);
        bool ok = true;
        #pragma unroll
        for (int i = 0; i < SROWS; ++i) {
          u32 a0 = (u32)hreg[i], a1 = (u32)(hreg[i] >> 32);
          ok = ok && (TAG2(a0) == texp) && (TAG2(a1) == texp);
        }
        if (__all(ok)) break;
      }
      POLL_FENCE();
      #pragma unroll
      for (int i = 0; i < SROWS; ++i) {
        u32 v0 = (u32)hreg[i], v1 = (u32)(hreg[i] >> 32);
        *(u32*)&sHh[i][tid * 2] = (v0 >> 16) | (v1 & 0xFFFF0000u);
        *(u32*)&sHl[i][tid * 2] = (v0 & 0xFFFFu) | (v1 << 16);
      }
    }
    __syncthreads();

    // ---- R,Z GEMM (k-split wave pairs) ----
    f32x4 aR = {0.f, 0.f, 0.f, 0.f}, aZ = {0.f, 0.f, 0.f, 0.f};
    if (kh == 0) {
      #pragma unroll
      for (int ks = 0; ks < 3; ++ks) {
        int kk = ks * 32 + rquad * 8;
        bf16x8 xrh = bc8(*(const uint4*)&sX[0][0][rowl][kk]);
        bf16x8 xrl = bc8(*(const uint4*)&sX[0][1][rowl][kk]);
        bf16x8 xzh = bc8(*(const uint4*)&sX[1][0][rowl][kk]);
        bf16x8 xzl = bc8(*(const uint4*)&sX[1][1][rowl][kk]);
        bf16x8 wrh = bc8(*(const uint4*)&WXRh[(size_t)scol * DPAD + kk]);
        bf16x8 wrl = bc8(*(const uint4*)&WXRl[(size_t)scol * DPAD + kk]);
        bf16x8 wzh = bc8(*(const uint4*)&WXZh[(size_t)scol * DPAD + kk]);
        bf16x8 wzl = bc8(*(const uint4*)&WXZl[(size_t)scol * DPAD + kk]);
        aR = mfma_bf16(xrh, wrh, aR); aR = mfma_bf16(xrl, wrh, aR); aR = mfma_bf16(xrh, wrl, aR);
        aZ = mfma_bf16(xzh, wzh, aZ); aZ = mfma_bf16(xzl, wzh, aZ); aZ = mfma_bf16(xzh, wzl, aZ);
      }
    }
    #pragma unroll
    for (int c = 0; c < 8; ++c) {
      int k = (kh * 8 + c) * 32 + rquad * 8;
      bf16x8 ah = bc8(*(const uint4*)&sHh[rowl][k]);
      bf16x8 al = bc8(*(const uint4*)&sHl[rowl][k]);
      bf16x8 bwR = bc8(*(const uint4*)&WR[(size_t)scol * HID + k]);
      bf16x8 bwZ = bc8(*(const uint4*)&WZ[(size_t)scol * HID + k]);
      aR = mfma_bf16(ah, bwR, aR); aR = mfma_bf16(al, bwR, aR);
      aZ = mfma_bf16(ah, bwZ, aZ); aZ = mfma_bf16(al, bwZ, aZ);
    }
    if (kh == 1) {
      *(f32x4*)&sC[0][ct][lane][0] = aR;
      *(f32x4*)&sC[1][ct][lane][0] = aZ;
    }
    __syncthreads();

    // ---- epilogue A (kh==0): sigmoid, z->regs, g = R*h_precise, tagged store ----
    if (kh == 0) {
      f32x4 oR = *(const f32x4*)&sC[0][ct][lane][0];
      f32x4 oZ = *(const f32x4*)&sC[1][ct][lane][0];
      u32* gdst = g_pk + (size_t)(t & 1) * NB * HID;
      #pragma unroll
      for (int r = 0; r < 4; ++r) {
        int rowm = rquad * 4 + r;
        float Rv = fsigmoid(aR[r] + oR[r] + bRv);
        zv[r]    = fsigmoid(aZ[r] + oZ[r] + bZv);
        float hprec = bf2f(sHh[rowm][scol]) + bf2f(sHl[rowm][scol]);
        u32 gp = pack_tagged(Rv * hprec, tg, nullptr);
        st_u32_llc(&gdst[(size_t)(strip * SROWS + rowm) * HID + scol], gp);
      }
    }

    // ---- phase C (small-ws): out(t-2) from h(t-1) read out of validated LDS ----
    if (do_c && t >= 2) {
      __syncthreads();                         // sC combine reads done; sH reads continue (RO)
      float* scz = (float*)sC;
      const int o = tid >> 3, q = tid & 7;
      float a = 0.f;
      #pragma unroll 8
      for (int k2 = 0; k2 < 64; ++k2) {
        int k = q * 64 + k2;
        a += (bf2f(sHh[part][k]) + bf2f(sHl[part][k])) * Wro[(size_t)o * HID + k];
      }
      scz[o * 8 + q] = a;
      if (tid < 8) {
        float a2 = 0.f;
        #pragma unroll 8
        for (int k2 = 0; k2 < 64; ++k2) {
          int k = tid * 64 + k2;
          a2 += (bf2f(sHh[part][k]) + bf2f(sHl[part][k])) * Wro[(size_t)32 * HID + k];
        }
        scz[256 + tid] = a2;
      }
      __syncthreads();
      if (tid < ODIM) {
        float s = bro[tid];
        #pragma unroll
        for (int q2 = 0; q2 < 8; ++q2) s += scz[tid * 8 + q2];
        out[(size_t)((t - 2) * NB + strip * SROWS + part) * ODIM + tid] = s;
      }
    }

    // ================= PHASE B: stage g(t) with tag-retry =================
    u64 greg[SROWS];
    {
      const u64* gsrc = (const u64*)(g_pk + (size_t)(t & 1) * NB * HID)
                        + (size_t)strip * SROWS * 256;
      for (;;) {
        #pragma unroll
        for (int i = 0; i < SROWS; ++i)
          greg[i] = ld_u64_llc(&gsrc[(size_t)i * 256 + tid]);
        bool ok = true;
        #pragma unroll
        for (int i = 0; i < SROWS; ++i) {
          u32 a0 = (u32)greg[i], a1 = (u32)(greg[i] >> 32);
          ok = ok && (TAG2(a0) == tg) && (TAG2(a1) == tg);
        }
        if (__all(ok)) break;
      }
      POLL_FENCE();
    }
    __syncthreads();          // all sH readers (GEMM, g-product, phase C) done before overwrite
    #pragma unroll
    for (int i = 0; i < SROWS; ++i) {
      u32 v0 = (u32)greg[i], v1 = (u32)(greg[i] >> 32);
      *(u32*)&sGh[i][tid * 2] = (v0 >> 16) | (v1 & 0xFFFF0000u);
      *(u32*)&sGl[i][tid * 2] = (v0 & 0xFFFFu) | (v1 << 16);
    }
    __syncthreads();

    // ---- Hhat GEMM (k-split) ----
    f32x4 aH = {0.f, 0.f, 0.f, 0.f};
    if (kh == 0) {
      #pragma unroll
      for (int ks = 0; ks < 3; ++ks) {
        int kk = ks * 32 + rquad * 8;
        bf16x8 xhh = bc8(*(const uint4*)&sX[2][0][rowl][kk]);
        bf16x8 xhl = bc8(*(const uint4*)&sX[2][1][rowl][kk]);
        bf16x8 whh = bc8(*(const uint4*)&WXHh[(size_t)scol * DPAD + kk]);
        bf16x8 whl = bc8(*(const uint4*)&WXHl[(size_t)scol * DPAD + kk]);
        aH = mfma_bf16(xhh, whh, aH);
        aH = mfma_bf16(xhl, whh, aH);
        aH = mfma_bf16(xhh, whl, aH);
      }
    }
    #pragma unroll
    for (int c = 0; c < 8; ++c) {
      int k = (kh * 8 + c) * 32 + rquad * 8;
      bf16x8 gh8 = bc8(*(const uint4*)&sGh[rowl][k]);
      bf16x8 gl8 = bc8(*(const uint4*)&sGl[rowl][k]);
      bf16x8 bwH = bc8(*(const uint4*)&WH[(size_t)scol * HID + k]);
      aH = mfma_bf16(gh8, bwH, aH);
      aH = mfma_bf16(gl8, bwH, aH);
    }
    if (kh == 1) *(f32x4*)&sC[0][ct][lane][0] = aH;
    __syncthreads();

    // ---- epilogue B (kh==0): tanh, gate, tagged h(t) store ----
    u16 hiv[4];
    if (kh == 0) {
      f32x4 oH = *(const f32x4*)&sC[0][ct][lane][0];
      u32* hdst = h_pk + (size_t)(t & 1) * NB * HID;
      #pragma unroll
      for (int r = 0; r < 4; ++r) {
        int rowm = rquad * 4 + r;
        float Hv = ftanh(aH[r] + oH[r] + bHv);
        float hn = zv[r] * h_old[r] + (1.0f - zv[r]) * Hv;
        h_old[r] = hn;
        u32 hp = pack_tagged(hn, tg, &hiv[r]);
        st_u32_llc(&hdst[(size_t)(strip * SROWS + rowm) * HID + scol], hp);
      }
    }

    // off critical path: hs_out (clean hi) + stage x(t+1)
    if (hs_out && kh == 0) {
      #pragma unroll
      for (int r = 0; r < 4; ++r)
        hs_out[(size_t)((t - 1) * NB + strip * SROWS + rquad * 4 + r) * HID + scol] = hiv[r];
    }
    if (t < TSTEPS) {
      const size_t xbase = ((size_t)t * NB + strip * SROWS) * DIN;
      for (int c = tid; c < 3 * SROWS * DIN; c += 256) {
        int g = c / (SROWS * DIN), rem = c - g * (SROWS * DIN);
        int row = rem / DIN, k = rem - row * DIN;
        const float* nsrc = (g == 0) ? nr : ((g == 1) ? nz : nh);
        float v = x[xbase + rem] + nsrc[xbase + rem];
        u16 hi = f2bf(v);
        sX[g][0][row][k] = hi;
        sX[g][1][row][k] = f2bf(v - bf2f(hi));
      }
    }
    __syncthreads();
  }

  // ---- final phase C (small-ws): out(TSTEPS-1) from h(TSTEPS) ----
  if (do_c) {
    const u32 texp = (u32)(TSTEPS & 3);
    const u64* hrow = (const u64*)(h_pk + (size_t)(TSTEPS & 1) * NB * HID)
                      + (size_t)(strip * SROWS + part) * 256;
    u64 v;
    for (;;) {
      v = ld_u64_llc(&hrow[tid]);
      u32 a0 = (u32)v, a1 = (u32)(v >> 32);
      if (__all((TAG2(a0) == texp) && (TAG2(a1) == texp))) break;
    }
    POLL_FENCE();
    __syncthreads();
    float* scz = (float*)sC;    // [0..511] row values, [512..783] partials
    {
      u32 a0 = (u32)v, a1 = (u32)(v >> 32);
      scz[tid * 2]     = bf2f((u16)(a0 >> 16)) + bf2f((u16)(a0 & 0xFFFFu));
      scz[tid * 2 + 1] = bf2f((u16)(a1 >> 16)) + bf2f((u16)(a1 & 0xFFFFu));
    }
    __syncthreads();
    float* sp = scz + 512;
    const int o = tid >> 3, q = tid & 7;
    float a = 0.f;
    #pragma unroll 8
    for (int k2 = 0; k2 < 64; ++k2) {
      int k = q * 64 + k2;
      a += scz[k] * Wro[(size_t)o * HID + k];
    }
    sp[o * 8 + q] = a;
    if (tid < 8) {
      float a2 = 0.f;
      #pragma unroll 8
      for (int k2 = 0; k2 < 64; ++k2) {
        int k = tid * 64 + k2;
        a2 += scz[k] * Wro[(size_t)32 * HID + k];
      }
      sp[256 + tid] = a2;
    }
    __syncthreads();
    if (tid < ODIM) {
      float s = bro[tid];
      #pragma unroll
      for (int q2 = 0; q2 < 8; ++q2) s += sp[tid * 8 + q2];
      out[(size_t)((TSTEPS - 1) * NB + strip * SROWS + part) * ODIM + tid] = s;
    }
  }
}

// ---------------- output projection (big-ws path) ----------------
__global__ void __launch_bounds__(256) out_kernel(
    const u16* __restrict__ hs_out,
    const u16* __restrict__ w_rob, const float* __restrict__ b_ro,
    float* __restrict__ out)
{
  __shared__ __attribute__((aligned(16))) u16 sOh[128][72];

  const int m0   = blockIdx.x * 128;
  const int tid  = threadIdx.x;
  const int lane = tid & 63, wave = tid >> 6;

  f32x4 acc[2][3];
  for (int a = 0; a < 2; ++a) for (int b = 0; b < 3; ++b) acc[a][b] = {0.f, 0.f, 0.f, 0.f};

  for (int kc = 0; kc < 8; ++kc) {
    __syncthreads();
    #pragma unroll
    for (int i = 0; i < 4; ++i) {
      int c = tid + 256 * i; int row = c >> 3, seg = c & 7;
      *(uint4*)&sOh[row][seg * 8] =
        *(const uint4*)&hs_out[(size_t)(m0 + row) * HID + kc * 64 + seg * 8];
    }
    __syncthreads();
    #pragma unroll
    for (int ks = 0; ks < 2; ++ks) {
      int klocal = ks * 32 + 8 * (lane >> 4);
      int kglob  = kc * 64 + klocal;
      bf16x8 ah[2];
      #pragma unroll
      for (int mf = 0; mf < 2; ++mf) {
        int rowl = wave * 32 + mf * 16 + (lane & 15);
        ah[mf] = bc8(*(const uint4*)&sOh[rowl][klocal]);
      }
      #pragma unroll
      for (int nf = 0; nf < 3; ++nf) {
        int wrow = nf * 16 + (lane & 15);
        bf16x8 bw = bc8(*(const uint4*)&w_rob[(size_t)wrow * HID + kglob]);
        #pragma unroll
        for (int mf = 0; mf < 2; ++mf)
          acc[mf][nf] = mfma_bf16(ah[mf], bw, acc[mf][nf]);
      }
    }
  }
  for (int nf = 0; nf < 3; ++nf) {
    int o = nf * 16 + (lane & 15);
    if (o < ODIM) {
      float bb = b_ro[o];
      for (int mf = 0; mf < 2; ++mf)
        for (int r = 0; r < 4; ++r) {
          int R = m0 + wave * 32 + mf * 16 + (lane >> 4) * 4 + r;
          out[(size_t)R * ODIM + o] = acc[mf][nf][r] + bb;
        }
    }
  }
}

// ---------------- launcher ----------------
extern "C" void kernel_launch(void* const* d_in, const int* in_sizes, int n_in,
                              void* d_out, int out_size, void* d_ws, size_t ws_size,
                              hipStream_t stream)
{
  const float* x   = (const float*)d_in[0];
  const float* nr  = (const float*)d_in[1];
  const float* nz  = (const float*)d_in[2];
  const float* nh  = (const float*)d_in[3];
  const float* Wxr = (const float*)d_in[4];
  const float* Wxz = (const float*)d_in[5];
  const float* Wxh = (const float*)d_in[6];
  const float* Whr = (const float*)d_in[7];
  const float* bhr = (const float*)d_in[8];
  const float* Whz = (const float*)d_in[9];
  const float* bhz = (const float*)d_in[10];
  const float* Whh = (const float*)d_in[11];
  const float* bhh = (const float*)d_in[12];
  const float* Wro = (const float*)d_in[13];
  const float* bro = (const float*)d_in[14];
  float* out = (float*)d_out;

  char* ws = (char*)d_ws;
  size_t off = 0;
  auto alloc = [&](size_t bytes) -> char* {
    char* p = ws + off;
    off += (bytes + 255) & ~(size_t)255;
    return p;
  };
  u32*  h_pk  = (u32*) alloc((size_t)2 * NB * HID * 4);   // tagged, double-buffered
  u32*  g_pk  = (u32*) alloc((size_t)2 * NB * HID * 4);   // tagged, double-buffered
  u16*  w_hb  = (u16*) alloc((size_t)3 * HID * HID * 2);
  u16*  wx_hi = (u16*) alloc((size_t)3 * HID * DPAD * 2);
  u16*  wx_lo = (u16*) alloc((size_t)3 * HID * DPAD * 2);
  u16*  w_rob = (u16*) alloc((size_t)OPAD * HID * 2);
  size_t small_need = off;
  if (ws_size < small_need) return;   // fail numerically, never scribble

  u16* hs_out = (u16*)(ws + off);
  size_t big_need = off + (size_t)TBROWS * HID * 2 + 256;
  bool big = (ws_size >= big_need);
  if (!big) hs_out = nullptr;

  hipMemsetAsync(h_pk, 0, (size_t)NB * HID * 4, stream);   // plane 0 = h(0) = 0, tag 0

  prep_kernel<<<512, 256, 0, stream>>>(Whr, Whz, Whh, Wxr, Wxz, Wxh, Wro,
                                       w_hb, wx_hi, wx_lo, w_rob);

  recur_kernel<<<NBLK, 256, 0, stream>>>(
      x, nr, nz, nh, bhr, bhz, bhh, wx_hi, wx_lo, w_hb,
      h_pk, g_pk, hs_out, Wro, bro, out, big ? 0 : 1);

  if (big)
    out_kernel<<<TBROWS / 128, 256, 0, stream>>>(hs_out, w_rob, bro, out);
}

// Round 11
// 8409.769 us; speedup vs baseline: 1.0668x; 1.0668x over previous
//
#include <hip/hip_runtime.h>
#include <stdint.h>

// ---------------- problem constants ----------------
#define TSTEPS 512
#define NB     256
#define DIN    85
#define DPAD   96
#define HID    512
#define ODIM   33
#define OPAD   48
#define TBROWS (TSTEPS*NB)
#define NBLK   256          // 16 strips x 16 parts
#define SROWS  16
#define LROW   520          // padded LDS row stride (u16)

typedef unsigned int u32;
typedef unsigned short u16;
typedef unsigned long long u64;
typedef __bf16 bf16x8 __attribute__((ext_vector_type(8)));
typedef float  f32x4  __attribute__((ext_vector_type(4)));

__device__ __forceinline__ u16 f2bf(float f) {
  u32 u = __float_as_uint(f);
  return (u16)((u + 0x7FFFu + ((u >> 16) & 1u)) >> 16);   // RNE
}
__device__ __forceinline__ float bf2f(u16 h) {
  return __uint_as_float(((u32)h) << 16);
}
__device__ __forceinline__ bf16x8 bc8(uint4 v) { return __builtin_bit_cast(bf16x8, v); }
__device__ __forceinline__ f32x4 mfma_bf16(bf16x8 a, bf16x8 b, f32x4 c) {
  return __builtin_amdgcn_mfma_f32_16x16x32_bf16(a, b, c, 0, 0, 0);
}
__device__ __forceinline__ float fsigmoid(float x) { return 1.0f / (1.0f + __expf(-x)); }
__device__ __forceinline__ float ftanh(float x)    { return 2.0f / (1.0f + __expf(-2.0f*x)) - 1.0f; }

// agent-scope (LLC-coherent) relaxed ops for cross-block mutable data
__device__ __forceinline__ void st_u32_llc(u32* p, u32 v) {
  __hip_atomic_store(p, v, __ATOMIC_RELAXED, __HIP_MEMORY_SCOPE_AGENT);
}
__device__ __forceinline__ u32 ld_u32_llc(const u32* p) {
  return __hip_atomic_load(p, __ATOMIC_RELAXED, __HIP_MEMORY_SCOPE_AGENT);
}
__device__ __forceinline__ u64 ld_u64_llc(const u64* p) {
  return __hip_atomic_load(p, __ATOMIC_RELAXED, __HIP_MEMORY_SCOPE_AGENT);
}
#define POLL_FENCE() do { asm volatile("" ::: "memory"); __builtin_amdgcn_sched_barrier(0); } while (0)
// raw barrier: sync waves WITHOUT draining vmem (flag is a hint; tags are truth)
__device__ __forceinline__ void raw_barrier() {
  asm volatile("" ::: "memory");
  __builtin_amdgcn_s_barrier();
  asm volatile("" ::: "memory");
}

// 2-bit generation tag in a packed (hi16|lo16) u32: bit16 (hi LSB) + bit0 (lo LSB)
#define TAG2(u) ((((u) >> 15) & 2u) | ((u) & 1u))
__device__ __forceinline__ u32 pack_tagged(float v, u32 tg, u16* hi_clean) {
  u16 hc = f2bf(v);
  if (hi_clean) *hi_clean = hc;
  u16 hi = (u16)((hc & 0xFFFEu) | ((tg >> 1) & 1u));
  u16 lo = f2bf(v - bf2f(hi));
  lo = (u16)((lo & 0xFFFEu) | (tg & 1u));
  return ((u32)hi << 16) | (u32)lo;
}

// ---------------- prep: bf16 weight conversions ----------------
__global__ void __launch_bounds__(256) prep_kernel(
    const float* __restrict__ Whr, const float* __restrict__ Whz, const float* __restrict__ Whh,
    const float* __restrict__ Wxr, const float* __restrict__ Wxz, const float* __restrict__ Wxh,
    const float* __restrict__ Wro,
    u16* __restrict__ w_hb, u16* __restrict__ wx_hi, u16* __restrict__ wx_lo,
    u16* __restrict__ w_rob)
{
  int tid = blockIdx.x * blockDim.x + threadIdx.x;
  int np  = gridDim.x * blockDim.x;
  for (int i = tid; i < 3 * HID * HID; i += np) {
    int m = i / (HID * HID), r = i % (HID * HID);
    const float* src = (m == 0) ? Whr : ((m == 1) ? Whz : Whh);
    w_hb[i] = f2bf(src[r]);
  }
  for (int i = tid; i < 3 * HID * DPAD; i += np) {
    int m = i / (HID * DPAD), r = i % (HID * DPAD);
    int row = r / DPAD, k = r % DPAD;
    const float* src = (m == 0) ? Wxr : ((m == 1) ? Wxz : Wxh);
    u16 hi = 0, lo = 0;
    if (k < DIN) {
      float v = src[row * DIN + k];
      hi = f2bf(v);
      lo = f2bf(v - bf2f(hi));
    }
    wx_hi[i] = hi; wx_lo[i] = lo;
  }
  for (int i = tid; i < OPAD * HID; i += np) {
    int row = i / HID, k = i % HID;
    w_rob[i] = (row < ODIM) ? f2bf(Wro[row * HID + k]) : (u16)0;
  }
}

// tagged staged load with selective retry (reload only stale u64s)
#define TAGGED_STAGE(REG, SRC, TEXP) do {                                     \
  bool bad_[SROWS];                                                           \
  _Pragma("unroll")                                                           \
  for (int i_ = 0; i_ < SROWS; ++i_) bad_[i_] = true;                         \
  for (;;) {                                                                  \
    _Pragma("unroll")                                                         \
    for (int i_ = 0; i_ < SROWS; ++i_)                                        \
      if (bad_[i_]) REG[i_] = ld_u64_llc(&SRC[(size_t)i_ * 256 + tid]);       \
    bool allok_ = true;                                                       \
    _Pragma("unroll")                                                         \
    for (int i_ = 0; i_ < SROWS; ++i_) {                                      \
      u32 a0_ = (u32)REG[i_], a1_ = (u32)(REG[i_] >> 32);                     \
      bad_[i_] = (TAG2(a0_) != (TEXP)) || (TAG2(a1_) != (TEXP));              \
      allok_ = allok_ && !bad_[i_];                                           \
    }                                                                         \
    if (__all(allok_)) break;                                                 \
  }                                                                           \
  POLL_FENCE();                                                               \
} while (0)

// ---------------- persistent recurrence kernel ----------------
__global__ void __launch_bounds__(256, 1) recur_kernel(
    const float* __restrict__ x,  const float* __restrict__ nr,
    const float* __restrict__ nz, const float* __restrict__ nh,
    const float* __restrict__ bhr, const float* __restrict__ bhz, const float* __restrict__ bhh,
    const u16* __restrict__ wx_hi, const u16* __restrict__ wx_lo, const u16* __restrict__ w_hb,
    u32* __restrict__ h_pk, u32* __restrict__ g_pk, u32* __restrict__ flags,
    u16* __restrict__ hs_out,
    const float* __restrict__ Wro, const float* __restrict__ bro, float* __restrict__ out,
    int do_c)
{
  __shared__ __attribute__((aligned(16))) u16 sBig[2 * SROWS * LROW];   // 33280 B
  __shared__ __attribute__((aligned(16))) u16 sX[3][2][SROWS][104];     // 19968 B
  __shared__ __attribute__((aligned(16))) float sC[2][2][64][4];        // 4096 B

  u16 (*sHh)[LROW] = (u16(*)[LROW])sBig;
  u16 (*sHl)[LROW] = (u16(*)[LROW])(sBig + SROWS * LROW);
  u16 (*sGh)[LROW] = sHh;
  u16 (*sGl)[LROW] = sHl;

  const int tid  = threadIdx.x;
  const int lane = tid & 63;
  const int wave = tid >> 6;
  const int strip = (int)blockIdx.x >> 4;    // 0..15
  const int part  = (int)blockIdx.x & 15;    // 0..15
  const int kh = wave >> 1;                  // k-half
  const int ct = wave & 1;                   // col-tile
  const int rowl  = lane & 15;
  const int rquad = lane >> 4;
  const int scol  = part * 32 + ct * 16 + rowl;

  u32* flagA = flags + strip * 32;           // g hint
  u32* flagB = flags + strip * 32 + 16;      // h hint

  const u16* WR = w_hb;
  const u16* WZ = w_hb + (size_t)HID * HID;
  const u16* WH = w_hb + (size_t)2 * HID * HID;
  const u16* WXRh = wx_hi;                          const u16* WXRl = wx_lo;
  const u16* WXZh = wx_hi + (size_t)HID * DPAD;     const u16* WXZl = wx_lo + (size_t)HID * DPAD;
  const u16* WXHh = wx_hi + (size_t)2 * HID * DPAD; const u16* WXHl = wx_lo + (size_t)2 * HID * DPAD;

  const float bRv = bhr[scol], bZv = bhz[scol], bHv = bhh[scol];

  float h_old[4] = {0.f, 0.f, 0.f, 0.f};
  float zv[4]    = {0.f, 0.f, 0.f, 0.f};

  // zero x k-pads once
  for (int c = tid; c < 3 * 2 * SROWS * (104 - DIN); c += 256) {
    int g = c / (2 * SROWS * 19), r1 = c % (2 * SROWS * 19);
    int pl = r1 / (SROWS * 19),   r2 = r1 % (SROWS * 19);
    int row = r2 / 19, k = DIN + r2 % 19;
    sX[g][pl][row][k] = 0;
  }
  // stage x(1)
  {
    const size_t xbase = (size_t)(strip * SROWS) * DIN;
    for (int c = tid; c < 3 * SROWS * DIN; c += 256) {
      int g = c / (SROWS * DIN), rem = c - g * (SROWS * DIN);
      int row = rem / DIN, k = rem - row * DIN;
      const float* nsrc = (g == 0) ? nr : ((g == 1) ? nz : nh);
      float v = x[xbase + rem] + nsrc[xbase + rem];
      u16 hi = f2bf(v);
      sX[g][0][row][k] = hi;
      sX[g][1][row][k] = f2bf(v - bf2f(hi));
    }
  }
  __syncthreads();

  for (int t = 1; t <= TSTEPS; ++t) {
    const u32 tg = (u32)(t & 3);

    // ================= PHASE A =================
    // hint poll: h(t-1) likely ready
    if (t > 1) {
      const u32 target = (u32)(t - 1);
      for (;;) {
        u32 a = (lane < 16) ? ld_u32_llc(&flagB[lane]) : target;
        if (__all(a >= target)) break;
      }
      POLL_FENCE();
    }
    // tagged staged load of h(t-1)
    {
      const u32 texp = (u32)((t - 1) & 3);
      const u64* hsrc = (const u64*)(h_pk + (size_t)((t - 1) & 1) * NB * HID)
                        + (size_t)strip * SROWS * 256;
      u64 hreg[SROWS];
      TAGGED_STAGE(hreg, hsrc, texp);
      #pragma unroll
      for (int i = 0; i < SROWS; ++i) {
        u32 v0 = (u32)hreg[i], v1 = (u32)(hreg[i] >> 32);
        *(u32*)&sHh[i][tid * 2] = (v0 >> 16) | (v1 & 0xFFFF0000u);
        *(u32*)&sHl[i][tid * 2] = (v0 & 0xFFFFu) | (v1 << 16);
      }
    }
    __syncthreads();

    // R,Z GEMM (k-split wave pairs)
    f32x4 aR = {0.f, 0.f, 0.f, 0.f}, aZ = {0.f, 0.f, 0.f, 0.f};
    if (kh == 0) {
      #pragma unroll
      for (int ks = 0; ks < 3; ++ks) {
        int kk = ks * 32 + rquad * 8;
        bf16x8 xrh = bc8(*(const uint4*)&sX[0][0][rowl][kk]);
        bf16x8 xrl = bc8(*(const uint4*)&sX[0][1][rowl][kk]);
        bf16x8 xzh = bc8(*(const uint4*)&sX[1][0][rowl][kk]);
        bf16x8 xzl = bc8(*(const uint4*)&sX[1][1][rowl][kk]);
        bf16x8 wrh = bc8(*(const uint4*)&WXRh[(size_t)scol * DPAD + kk]);
        bf16x8 wrl = bc8(*(const uint4*)&WXRl[(size_t)scol * DPAD + kk]);
        bf16x8 wzh = bc8(*(const uint4*)&WXZh[(size_t)scol * DPAD + kk]);
        bf16x8 wzl = bc8(*(const uint4*)&WXZl[(size_t)scol * DPAD + kk]);
        aR = mfma_bf16(xrh, wrh, aR); aR = mfma_bf16(xrl, wrh, aR); aR = mfma_bf16(xrh, wrl, aR);
        aZ = mfma_bf16(xzh, wzh, aZ); aZ = mfma_bf16(xzl, wzh, aZ); aZ = mfma_bf16(xzh, wzl, aZ);
      }
    }
    #pragma unroll
    for (int c = 0; c < 8; ++c) {
      int k = (kh * 8 + c) * 32 + rquad * 8;
      bf16x8 ah = bc8(*(const uint4*)&sHh[rowl][k]);
      bf16x8 al = bc8(*(const uint4*)&sHl[rowl][k]);
      bf16x8 bwR = bc8(*(const uint4*)&WR[(size_t)scol * HID + k]);
      bf16x8 bwZ = bc8(*(const uint4*)&WZ[(size_t)scol * HID + k]);
      aR = mfma_bf16(ah, bwR, aR); aR = mfma_bf16(al, bwR, aR);
      aZ = mfma_bf16(ah, bwZ, aZ); aZ = mfma_bf16(al, bwZ, aZ);
    }
    if (kh == 1) {
      *(f32x4*)&sC[0][ct][lane][0] = aR;
      *(f32x4*)&sC[1][ct][lane][0] = aZ;
    }
    __syncthreads();

    // epilogue A (kh==0): sigmoid, z->regs, tagged g stores (NO drain after)
    if (kh == 0) {
      f32x4 oR = *(const f32x4*)&sC[0][ct][lane][0];
      f32x4 oZ = *(const f32x4*)&sC[1][ct][lane][0];
      u32* gdst = g_pk + (size_t)(t & 1) * NB * HID;
      #pragma unroll
      for (int r = 0; r < 4; ++r) {
        int rowm = rquad * 4 + r;
        float Rv = fsigmoid(aR[r] + oR[r] + bRv);
        zv[r]    = fsigmoid(aZ[r] + oZ[r] + bZv);
        float hprec = bf2f(sHh[rowm][scol]) + bf2f(sHl[rowm][scol]);
        u32 gp = pack_tagged(Rv * hprec, tg, nullptr);
        st_u32_llc(&gdst[(size_t)(strip * SROWS + rowm) * HID + scol], gp);
      }
    }
    raw_barrier();                       // all waves issued g stores (no ack wait)
    if (tid == 0) st_u32_llc(&flagA[part], (u32)t);

    // phase C (small-ws): out(t-2) from validated sH planes — fills the g-handoff window
    if (do_c && t >= 2) {
      float* scz = (float*)sC;
      const int o = tid >> 3, q = tid & 7;
      float a = 0.f;
      #pragma unroll 8
      for (int k2 = 0; k2 < 64; ++k2) {
        int k = q * 64 + k2;
        a += (bf2f(sHh[part][k]) + bf2f(sHl[part][k])) * Wro[(size_t)o * HID + k];
      }
      scz[o * 8 + q] = a;
      if (tid < 8) {
        float a2 = 0.f;
        #pragma unroll 8
        for (int k2 = 0; k2 < 64; ++k2) {
          int k = tid * 64 + k2;
          a2 += (bf2f(sHh[part][k]) + bf2f(sHl[part][k])) * Wro[(size_t)32 * HID + k];
        }
        scz[256 + tid] = a2;
      }
      __syncthreads();
      if (tid < ODIM) {
        float s = bro[tid];
        #pragma unroll
        for (int q2 = 0; q2 < 8; ++q2) s += scz[tid * 8 + q2];
        out[(size_t)((t - 2) * NB + strip * SROWS + part) * ODIM + tid] = s;
      }
    }

    // ================= PHASE B =================
    // hint poll: g(t) likely ready
    {
      const u32 target = (u32)t;
      for (;;) {
        u32 a = (lane < 16) ? ld_u32_llc(&flagA[lane]) : target;
        if (__all(a >= target)) break;
      }
      POLL_FENCE();
    }
    // tagged staged load of g(t)
    u64 greg[SROWS];
    {
      const u64* gsrc = (const u64*)(g_pk + (size_t)(t & 1) * NB * HID)
                        + (size_t)strip * SROWS * 256;
      TAGGED_STAGE(greg, gsrc, tg);
    }
    __syncthreads();          // all sH readers (GEMM epilogue, phase C) done before overwrite
    #pragma unroll
    for (int i = 0; i < SROWS; ++i) {
      u32 v0 = (u32)greg[i], v1 = (u32)(greg[i] >> 32);
      *(u32*)&sGh[i][tid * 2] = (v0 >> 16) | (v1 & 0xFFFF0000u);
      *(u32*)&sGl[i][tid * 2] = (v0 & 0xFFFFu) | (v1 << 16);
    }
    __syncthreads();

    // Hhat GEMM (k-split)
    f32x4 aH = {0.f, 0.f, 0.f, 0.f};
    if (kh == 0) {
      #pragma unroll
      for (int ks = 0; ks < 3; ++ks) {
        int kk = ks * 32 + rquad * 8;
        bf16x8 xhh = bc8(*(const uint4*)&sX[2][0][rowl][kk]);
        bf16x8 xhl = bc8(*(const uint4*)&sX[2][1][rowl][kk]);
        bf16x8 whh = bc8(*(const uint4*)&WXHh[(size_t)scol * DPAD + kk]);
        bf16x8 whl = bc8(*(const uint4*)&WXHl[(size_t)scol * DPAD + kk]);
        aH = mfma_bf16(xhh, whh, aH);
        aH = mfma_bf16(xhl, whh, aH);
        aH = mfma_bf16(xhh, whl, aH);
      }
    }
    #pragma unroll
    for (int c = 0; c < 8; ++c) {
      int k = (kh * 8 + c) * 32 + rquad * 8;
      bf16x8 gh8 = bc8(*(const uint4*)&sGh[rowl][k]);
      bf16x8 gl8 = bc8(*(const uint4*)&sGl[rowl][k]);
      bf16x8 bwH = bc8(*(const uint4*)&WH[(size_t)scol * HID + k]);
      aH = mfma_bf16(gh8, bwH, aH);
      aH = mfma_bf16(gl8, bwH, aH);
    }
    if (kh == 1) *(f32x4*)&sC[0][ct][lane][0] = aH;
    __syncthreads();

    // epilogue B (kh==0): tanh, gate, tagged h(t) stores (NO drain after)
    u16 hiv[4];
    if (kh == 0) {
      f32x4 oH = *(const f32x4*)&sC[0][ct][lane][0];
      u32* hdst = h_pk + (size_t)(t & 1) * NB * HID;
      #pragma unroll
      for (int r = 0; r < 4; ++r) {
        int rowm = rquad * 4 + r;
        float Hv = ftanh(aH[r] + oH[r] + bHv);
        float hn = zv[r] * h_old[r] + (1.0f - zv[r]) * Hv;
        h_old[r] = hn;
        u32 hp = pack_tagged(hn, tg, &hiv[r]);
        st_u32_llc(&hdst[(size_t)(strip * SROWS + rowm) * HID + scol], hp);
      }
    }
    raw_barrier();
    if (tid == 0) st_u32_llc(&flagB[part], (u32)t);

    // off critical path: hs_out (clean hi) + stage x(t+1)
    if (hs_out && kh == 0) {
      #pragma unroll
      for (int r = 0; r < 4; ++r)
        hs_out[(size_t)((t - 1) * NB + strip * SROWS + rquad * 4 + r) * HID + scol] = hiv[r];
    }
    if (t < TSTEPS) {
      const size_t xbase = ((size_t)t * NB + strip * SROWS) * DIN;
      for (int c = tid; c < 3 * SROWS * DIN; c += 256) {
        int g = c / (SROWS * DIN), rem = c - g * (SROWS * DIN);
        int row = rem / DIN, k = rem - row * DIN;
        const float* nsrc = (g == 0) ? nr : ((g == 1) ? nz : nh);
        float v = x[xbase + rem] + nsrc[xbase + rem];
        u16 hi = f2bf(v);
        sX[g][0][row][k] = hi;
        sX[g][1][row][k] = f2bf(v - bf2f(hi));
      }
    }
    __syncthreads();
  }

  // ---- final phase C (small-ws): out(TSTEPS-1) from h(TSTEPS) ----
  if (do_c) {
    const u32 texp = (u32)(TSTEPS & 3);
    {
      const u32 target = (u32)TSTEPS;
      for (;;) {
        u32 a = (lane < 16) ? ld_u32_llc(&flagB[lane]) : target;
        if (__all(a >= target)) break;
      }
      POLL_FENCE();
    }
    const u64* hrow = (const u64*)(h_pk + (size_t)(TSTEPS & 1) * NB * HID)
                      + (size_t)(strip * SROWS + part) * 256;
    u64 v;
    for (;;) {
      v = ld_u64_llc(&hrow[tid]);
      u32 a0 = (u32)v, a1 = (u32)(v >> 32);
      if (__all((TAG2(a0) == texp) && (TAG2(a1) == texp))) break;
    }
    POLL_FENCE();
    __syncthreads();
    float* scz = (float*)sC;
    {
      u32 a0 = (u32)v, a1 = (u32)(v >> 32);
      scz[tid * 2]     = bf2f((u16)(a0 >> 16)) + bf2f((u16)(a0 & 0xFFFFu));
      scz[tid * 2 + 1] = bf2f((u16)(a1 >> 16)) + bf2f((u16)(a1 & 0xFFFFu));
    }
    __syncthreads();
    float* sp = scz + 512;
    const int o = tid >> 3, q = tid & 7;
    float a = 0.f;
    #pragma unroll 8
    for (int k2 = 0; k2 < 64; ++k2) {
      int k = q * 64 + k2;
      a += scz[k] * Wro[(size_t)o * HID + k];
    }
    sp[o * 8 + q] = a;
    if (tid < 8) {
      float a2 = 0.f;
      #pragma unroll 8
      for (int k2 = 0; k2 < 64; ++k2) {
        int k = tid * 64 + k2;
        a2 += scz[k] * Wro[(size_t)32 * HID + k];
      }
      sp[256 + tid] = a2;
    }
    __syncthreads();
    if (tid < ODIM) {
      float s = bro[tid];
      #pragma unroll
      for (int q2 = 0; q2 < 8; ++q2) s += sp[tid * 8 + q2];
      out[(size_t)((TSTEPS - 1) * NB + strip * SROWS + part) * ODIM + tid] = s;
    }
  }
}

// ---------------- output projection (big-ws path) ----------------
__global__ void __launch_bounds__(256) out_kernel(
    const u16* __restrict__ hs_out,
    const u16* __restrict__ w_rob, const float* __restrict__ b_ro,
    float* __restrict__ out)
{
  __shared__ __attribute__((aligned(16))) u16 sOh[128][72];

  const int m0   = blockIdx.x * 128;
  const int tid  = threadIdx.x;
  const int lane = tid & 63, wave = tid >> 6;

  f32x4 acc[2][3];
  for (int a = 0; a < 2; ++a) for (int b = 0; b < 3; ++b) acc[a][b] = {0.f, 0.f, 0.f, 0.f};

  for (int kc = 0; kc < 8; ++kc) {
    __syncthreads();
    #pragma unroll
    for (int i = 0; i < 4; ++i) {
      int c = tid + 256 * i; int row = c >> 3, seg = c & 7;
      *(uint4*)&sOh[row][seg * 8] =
        *(const uint4*)&hs_out[(size_t)(m0 + row) * HID + kc * 64 + seg * 8];
    }
    __syncthreads();
    #pragma unroll
    for (int ks = 0; ks < 2; ++ks) {
      int klocal = ks * 32 + 8 * (lane >> 4);
      int kglob  = kc * 64 + klocal;
      bf16x8 ah[2];
      #pragma unroll
      for (int mf = 0; mf < 2; ++mf) {
        int rowl = wave * 32 + mf * 16 + (lane & 15);
        ah[mf] = bc8(*(const uint4*)&sOh[rowl][klocal]);
      }
      #pragma unroll
      for (int nf = 0; nf < 3; ++nf) {
        int wrow = nf * 16 + (lane & 15);
        bf16x8 bw = bc8(*(const uint4*)&w_rob[(size_t)wrow * HID + kglob]);
        #pragma unroll
        for (int mf = 0; mf < 2; ++mf)
          acc[mf][nf] = mfma_bf16(ah[mf], bw, acc[mf][nf]);
      }
    }
  }
  for (int nf = 0; nf < 3; ++nf) {
    int o = nf * 16 + (lane & 15);
    if (o < ODIM) {
      float bb = b_ro[o];
      for (int mf = 0; mf < 2; ++mf)
        for (int r = 0; r < 4; ++r) {
          int R = m0 + wave * 32 + mf * 16 + (lane >> 4) * 4 + r;
          out[(size_t)R * ODIM + o] = acc[mf][nf][r] + bb;
        }
    }
  }
}

// ---------------- launcher ----------------
extern "C" void kernel_launch(void* const* d_in, const int* in_sizes, int n_in,
                              void* d_out, int out_size, void* d_ws, size_t ws_size,
                              hipStream_t stream)
{
  const float* x   = (const float*)d_in[0];
  const float* nr  = (const float*)d_in[1];
  const float* nz  = (const float*)d_in[2];
  const float* nh  = (const float*)d_in[3];
  const float* Wxr = (const float*)d_in[4];
  const float* Wxz = (const float*)d_in[5];
  const float* Wxh = (const float*)d_in[6];
  const float* Whr = (const float*)d_in[7];
  const float* bhr = (const float*)d_in[8];
  const float* Whz = (const float*)d_in[9];
  const float* bhz = (const float*)d_in[10];
  const float* Whh = (const float*)d_in[11];
  const float* bhh = (const float*)d_in[12];
  const float* Wro = (const float*)d_in[13];
  const float* bro = (const float*)d_in[14];
  float* out = (float*)d_out;

  char* ws = (char*)d_ws;
  size_t off = 0;
  auto alloc = [&](size_t bytes) -> char* {
    char* p = ws + off;
    off += (bytes + 255) & ~(size_t)255;
    return p;
  };
  u32*  h_pk  = (u32*) alloc((size_t)2 * NB * HID * 4);   // tagged, double-buffered
  u32*  g_pk  = (u32*) alloc((size_t)2 * NB * HID * 4);   // tagged, double-buffered
  u16*  w_hb  = (u16*) alloc((size_t)3 * HID * HID * 2);
  u16*  wx_hi = (u16*) alloc((size_t)3 * HID * DPAD * 2);
  u16*  wx_lo = (u16*) alloc((size_t)3 * HID * DPAD * 2);
  u16*  w_rob = (u16*) alloc((size_t)OPAD * HID * 2);
  u32*  flags = (u32*) alloc((size_t)16 * 32 * 4);
  size_t small_need = off;
  if (ws_size < small_need) return;   // fail numerically, never scribble

  u16* hs_out = (u16*)(ws + off);
  size_t big_need = off + (size_t)TBROWS * HID * 2 + 256;
  bool big = (ws_size >= big_need);
  if (!big) hs_out = nullptr;

  // tag-0 ground state every launch: poison/replay-proof, h0 = 0 for free
  hipMemsetAsync(h_pk,  0, (size_t)2 * NB * HID * 4, stream);
  hipMemsetAsync(g_pk,  0, (size_t)2 * NB * HID * 4, stream);
  hipMemsetAsync(flags, 0, (size_t)16 * 32 * 4, stream);

  prep_kernel<<<512, 256, 0, stream>>>(Whr, Whz, Whh, Wxr, Wxz, Wxh, Wro,
                                       w_hb, wx_hi, wx_lo, w_rob);

  recur_kernel<<<NBLK, 256, 0, stream>>>(
      x, nr, nz, nh, bhr, bhz, bhh, wx_hi, wx_lo, w_hb,
      h_pk, g_pk, flags, hs_out, Wro, bro, out, big ? 0 : 1);

  if (big)
    out_kernel<<<TBROWS / 128, 256, 0, stream>>>(hs_out, w_rob, bro, out);
}